// Round 5
// baseline (529.406 us; speedup 1.0000x reference)
//
#include <hip/hip_runtime.h>

// N=65536, E=1048576, nfeat=64, nhid=128. Inputs fp32; edge_index int32.
// Aggregation: LDS-staged bucket binning (256 buckets of 256 nodes) +
// per-bucket LDS-atomic accumulate. GEMMs: bf16 MFMA 16x16x32, fp32 acc.

#define BN_EPS 1e-5f
#define NB   256      // buckets
#define CAP  5120     // per-bucket capacity (avg 4096, +16 sigma)

typedef float f4 __attribute__((ext_vector_type(4)));
typedef short bf8 __attribute__((ext_vector_type(8)));   // 8 bf16 = 4 VGPRs

__device__ inline short f2bf(float f) {
    unsigned u = __float_as_uint(f);
    u = u + 0x7fffu + ((u >> 16) & 1u);   // round-to-nearest-even
    return (short)(u >> 16);
}

// ---------------- kzero: zero int array ----------------
__global__ __launch_bounds__(256) void kzero(int* __restrict__ p, int n) {
    int i = blockIdx.x * 256 + threadIdx.x;
    if (i < n) p[i] = 0;
}

// ---------------- kbin: LDS-staged edge binning ----------------
// 256 blocks x 256 threads, 4096 edges/block. Packed edge:
// [31:24]=bucket, [23:8]=src, [7:0]=dst&255. Flush per-bucket contiguous runs.
__global__ __launch_bounds__(256) void kbin(const int* __restrict__ ei, int E,
                                            int* __restrict__ gcount,
                                            unsigned* __restrict__ pairs) {
    __shared__ int hist[256];
    __shared__ int sbase[256];
    __shared__ int cur[256];
    __shared__ int gofs[256];
    __shared__ unsigned stage[4096];
    int t = threadIdx.x;
    int e0 = blockIdx.x * 4096;

    hist[t] = 0;
    __syncthreads();

    unsigned pk[16];
    int bk[16];
#pragma unroll
    for (int i = 0; i < 16; i++) {
        int e = e0 + i * 256 + t;
        int src = ei[e];
        int dst = ei[E + e];
        int b = dst >> 8;
        bk[i] = b;
        pk[i] = ((unsigned)b << 24) | ((unsigned)src << 8) | (unsigned)(dst & 255);
        atomicAdd(&hist[b], 1);
    }
    __syncthreads();

    int cntb = hist[t];
    // inclusive Hillis-Steele scan over hist
    for (int off = 1; off < 256; off <<= 1) {
        int v = (t >= off) ? hist[t - off] : 0;
        __syncthreads();
        hist[t] += v;
        __syncthreads();
    }
    int excl = hist[t] - cntb;
    sbase[t] = excl;
    cur[t] = excl;
    __syncthreads();

    // place into bucket-sorted LDS stage
#pragma unroll
    for (int i = 0; i < 16; i++) {
        int p = atomicAdd(&cur[bk[i]], 1);
        stage[p] = pk[i];
    }
    __syncthreads();

    // reserve global run for bucket t
    gofs[t] = atomicAdd(&gcount[t], cntb);
    __syncthreads();

    // flush: consecutive stage entries -> consecutive global addresses per run
#pragma unroll
    for (int i = 0; i < 16; i++) {
        int p = i * 256 + t;
        unsigned v = stage[p];
        int b = (int)(v >> 24);
        int li = p - sbase[b];
        pairs[(size_t)b * CAP + gofs[b] + li] = v & 0xFFFFFFu;
    }
}

// ---------------- kaggb: per-bucket aggregate via LDS atomics ----------------
// One block per bucket (256 nodes), 512 threads (8 waves), 64 KB LDS fp32 acc.
// hbf[n] = bf16(x[n] + sum_{src->n} x[src])
__global__ __launch_bounds__(512) void kaggb(const unsigned* __restrict__ pairs,
                                             const int* __restrict__ gcount,
                                             const float* __restrict__ x,
                                             short* __restrict__ hbf) {
    __shared__ float acc[256 * 64];   // 64 KB
    int t = threadIdx.x;
    int b = blockIdx.x;
#pragma unroll
    for (int i = 0; i < 32; i++) acc[i * 512 + t] = 0.f;
    __syncthreads();

    int cnt = gcount[b];
    const unsigned* ep = pairs + (size_t)b * CAP;
    int w = t >> 6, lane = t & 63;

    int M = cnt & ~63;
    for (int j = w * 8; j + 8 <= M; j += 64) {
        unsigned v[8];
        float f[8];
#pragma unroll
        for (int u = 0; u < 8; u++) v[u] = ep[j + u];
#pragma unroll
        for (int u = 0; u < 8; u++) f[u] = x[(size_t)(v[u] >> 8) * 64 + lane];
#pragma unroll
        for (int u = 0; u < 8; u++)
            atomicAdd(&acc[(v[u] & 255u) * 64 + lane], f[u]);
    }
    for (int j = M + w; j < cnt; j += 8) {
        unsigned v = ep[j];
        float f = x[(size_t)(v >> 8) * 64 + lane];
        atomicAdd(&acc[(v & 255u) * 64 + lane], f);
    }
    __syncthreads();

    // writeout: packed 2x bf16, coalesced
    int n0 = b * 256;
    unsigned* dst = (unsigned*)hbf + (size_t)n0 * 32;
    const float* xb = x + (size_t)n0 * 64;
#pragma unroll
    for (int i = 0; i < 16; i++) {
        int idx = i * 512 + t;          // 0..8191
        float v0 = xb[idx * 2] + acc[idx * 2];
        float v1 = xb[idx * 2 + 1] + acc[idx * 2 + 1];
        unsigned p = (unsigned)(unsigned short)f2bf(v0) |
                     ((unsigned)(unsigned short)f2bf(v1) << 16);
        dst[idx] = p;
    }
}

// ---------------- kcvt: fp32 -> bf16 (for W1) ----------------
__global__ __launch_bounds__(256) void kcvt(const float* __restrict__ w,
                                            short* __restrict__ o, int n) {
    int i = blockIdx.x * 256 + threadIdx.x;
    if (i < n) o[i] = f2bf(w[i]);
}

// ---------------- K2: spectral-norm sigmas (1 block, 128 thr, fp32) ----------------
__global__ __launch_bounds__(128) void k2_sigma(const float* __restrict__ W1,
                                                const float* __restrict__ u1,
                                                const float* __restrict__ W2,
                                                const float* __restrict__ u2,
                                                float* __restrict__ sinv) {
    __shared__ float v[128];
    __shared__ float red[128];
    int t = threadIdx.x;

    float vj = 0.f;
    if (t < 64) {
        for (int i = 0; i < 128; i++) vj += W1[i * 64 + t] * u1[i];
    }
    red[t] = (t < 64) ? vj * vj : 0.f;
    __syncthreads();
    for (int s = 64; s > 0; s >>= 1) { if (t < s) red[t] += red[t + s]; __syncthreads(); }
    float nv = sqrtf(red[0]);
    __syncthreads();
    if (t < 64) v[t] = vj / (nv + 1e-12f);
    __syncthreads();
    float ti = 0.f;
    for (int j = 0; j < 64; j++) ti += W1[t * 64 + j] * v[j];
    red[t] = ti * ti;
    __syncthreads();
    for (int s = 64; s > 0; s >>= 1) { if (t < s) red[t] += red[t + s]; __syncthreads(); }
    if (t == 0) {
        float nt2 = red[0];
        float nt = sqrtf(nt2);
        sinv[0] = (nt + 1e-12f) / nt2;
    }
    __syncthreads();

    float v2 = 0.f;
    for (int i = 0; i < 128; i++) v2 += W2[i * 128 + t] * u2[i];
    red[t] = v2 * v2;
    __syncthreads();
    for (int s = 64; s > 0; s >>= 1) { if (t < s) red[t] += red[t + s]; __syncthreads(); }
    nv = sqrtf(red[0]);
    __syncthreads();
    v[t] = v2 / (nv + 1e-12f);
    __syncthreads();
    ti = 0.f;
    for (int j = 0; j < 128; j++) ti += W2[t * 128 + j] * v[j];
    red[t] = ti * ti;
    __syncthreads();
    for (int s = 64; s > 0; s >>= 1) { if (t < s) red[t] += red[t + s]; __syncthreads(); }
    if (t == 0) {
        float nt2 = red[0];
        float nt = sqrtf(nt2);
        sinv[1] = (nt + 1e-12f) / nt2;
    }
}

// ---------------- K3: h1 = relu(s1*(h @ W1^T) + b1) via MFMA + BN partials ----
__global__ __launch_bounds__(256) void k3_gemm1(const short* __restrict__ hbf,
                                                const short* __restrict__ w1bf,
                                                const float* __restrict__ b1,
                                                const float* __restrict__ sinv,
                                                short* __restrict__ h1bf,
                                                float* __restrict__ partial) {
    __shared__ short u[16384];          // 32 KB
    __shared__ float red1[512], red2[512];
    int t = threadIdx.x;
    int n0 = blockIdx.x * 128;

    const bf8* hsrc = (const bf8*)(hbf + (size_t)n0 * 64);
    const bf8* wsrc = (const bf8*)w1bf;
#pragma unroll
    for (int i = 0; i < 4; i++) {
        int idx = i * 256 + t;
        int row = idx >> 3, c = idx & 7;
        int cs = c ^ (row & 7);
        *(bf8*)&u[row * 64 + cs * 8] = hsrc[idx];
    }
#pragma unroll
    for (int i = 0; i < 4; i++) {
        int idx = i * 256 + t;
        int row = idx >> 3, c = idx & 7;
        int cs = c ^ (row & 7);
        *(bf8*)&u[8192 + row * 64 + cs * 8] = wsrc[idx];
    }
    __syncthreads();

    int w = t >> 6;
    int l15 = t & 15, quad = (t & 63) >> 4;

    f4 acc[2][8];
#pragma unroll
    for (int mt = 0; mt < 2; mt++)
#pragma unroll
        for (int nt = 0; nt < 8; nt++) acc[mt][nt] = (f4){0.f, 0.f, 0.f, 0.f};

#pragma unroll
    for (int ks = 0; ks < 2; ks++) {
        bf8 a[2], b[8];
#pragma unroll
        for (int mt = 0; mt < 2; mt++) {
            int node = w * 32 + mt * 16 + l15;
            int cs = (ks * 4 + quad) ^ (node & 7);
            a[mt] = *(const bf8*)&u[node * 64 + cs * 8];
        }
#pragma unroll
        for (int nt = 0; nt < 8; nt++) {
            int o = nt * 16 + l15;
            int cs = (ks * 4 + quad) ^ (o & 7);
            b[nt] = *(const bf8*)&u[8192 + o * 64 + cs * 8];
        }
#pragma unroll
        for (int mt = 0; mt < 2; mt++)
#pragma unroll
            for (int nt = 0; nt < 8; nt++)
                acc[mt][nt] = __builtin_amdgcn_mfma_f32_16x16x32_bf16(
                    a[mt], b[nt], acc[mt][nt], 0, 0, 0);
    }

    float s1 = sinv[0];
    float b1v[8];
#pragma unroll
    for (int nt = 0; nt < 8; nt++) b1v[nt] = b1[nt * 16 + l15];

#pragma unroll
    for (int nt = 0; nt < 8; nt++) {
        float s = 0.f, q = 0.f;
#pragma unroll
        for (int mt = 0; mt < 2; mt++)
#pragma unroll
            for (int r = 0; r < 4; r++) {
                float v = fmaxf(fmaf(acc[mt][nt][r], s1, b1v[nt]), 0.f);
                acc[mt][nt][r] = v;
                s += v; q += v * v;
            }
        s += __shfl_xor(s, 16); s += __shfl_xor(s, 32);
        q += __shfl_xor(q, 16); q += __shfl_xor(q, 32);
        if (quad == 0) {
            red1[w * 128 + nt * 16 + l15] = s;
            red2[w * 128 + nt * 16 + l15] = q;
        }
    }
    __syncthreads();

#pragma unroll
    for (int mt = 0; mt < 2; mt++)
#pragma unroll
        for (int nt = 0; nt < 8; nt++) {
            int col = nt * 16 + l15;
#pragma unroll
            for (int r = 0; r < 4; r++) {
                int node = w * 32 + mt * 16 + quad * 4 + r;
                int cs = (col >> 3) ^ (node & 15);
                u[node * 128 + cs * 8 + (col & 7)] = f2bf(acc[mt][nt][r]);
            }
        }
    __syncthreads();

    short* dst = h1bf + (size_t)n0 * 128;
#pragma unroll
    for (int i = 0; i < 8; i++) {
        int idx = i * 256 + t;
        int row = idx >> 4, c = idx & 15;
        int cs = c ^ (row & 15);
        *(bf8*)&dst[idx * 8] = *(const bf8*)&u[row * 128 + cs * 8];
    }
    if (t < 128) {
        float s = red1[t] + red1[128 + t] + red1[256 + t] + red1[384 + t];
        float q = red2[t] + red2[128 + t] + red2[256 + t] + red2[384 + t];
        partial[blockIdx.x * 256 + t] = s;
        partial[blockIdx.x * 256 + 128 + t] = q;
    }
}

// ---------------- K4: fold BN + sigma2 into W2f(bf16), b2f(fp32) ----------------
__global__ __launch_bounds__(256) void k4_fold(const float* __restrict__ partial,
                                               int nblk, int N,
                                               const float* __restrict__ gamma,
                                               const float* __restrict__ beta,
                                               const float* __restrict__ W2,
                                               const float* __restrict__ b2,
                                               const float* __restrict__ sinv,
                                               short* __restrict__ W2fbf,
                                               float* __restrict__ b2f) {
    __shared__ float sums[256];
    __shared__ float a_s[128], c_s[128];
    int t = threadIdx.x;
    float t0 = 0.f, t1 = 0.f, t2 = 0.f, t3 = 0.f;
    for (int b = 0; b < nblk; b += 4) {
        t0 += partial[(b + 0) * 256 + t];
        t1 += partial[(b + 1) * 256 + t];
        t2 += partial[(b + 2) * 256 + t];
        t3 += partial[(b + 3) * 256 + t];
    }
    sums[t] = (t0 + t1) + (t2 + t3);
    __syncthreads();
    if (t < 128) {
        float mean = sums[t] / (float)N;
        float var = sums[t + 128] / (float)N - mean * mean;
        float rstd = rsqrtf(var + BN_EPS);
        float a = rstd * gamma[t];
        a_s[t] = a;
        c_s[t] = beta[t] - mean * a;
    }
    __syncthreads();
    if (t < 128) {
        float s2 = sinv[1];
        float accb = 0.f;
        for (int j = 0; j < 128; j++) {
            float w = W2[t * 128 + j] * s2;
            W2fbf[t * 128 + j] = f2bf(w * a_s[j]);
            accb += w * c_s[j];
        }
        b2f[t] = b2[t] + accb;
    }
}

// ---------------- K5: out = h1 @ W2f^T + b2f via MFMA ----------------
__global__ __launch_bounds__(256) void k5_gemm2(const short* __restrict__ h1bf,
                                                const short* __restrict__ w2fbf,
                                                const float* __restrict__ b2f,
                                                float* __restrict__ out) {
    __shared__ short s5[32768];
    int t = threadIdx.x;
    int n0 = blockIdx.x * 128;

    const bf8* hsrc = (const bf8*)(h1bf + (size_t)n0 * 128);
    const bf8* wsrc = (const bf8*)w2fbf;
#pragma unroll
    for (int i = 0; i < 8; i++) {
        int idx = i * 256 + t;
        int row = idx >> 4, c = idx & 15;
        int cs = c ^ (row & 15);
        *(bf8*)&s5[row * 128 + cs * 8] = hsrc[idx];
    }
#pragma unroll
    for (int i = 0; i < 8; i++) {
        int idx = i * 256 + t;
        int row = idx >> 4, c = idx & 15;
        int cs = c ^ (row & 15);
        *(bf8*)&s5[16384 + row * 128 + cs * 8] = wsrc[idx];
    }
    __syncthreads();

    int w = t >> 6;
    int l15 = t & 15, quad = (t & 63) >> 4;

    f4 acc[2][8];
#pragma unroll
    for (int mt = 0; mt < 2; mt++)
#pragma unroll
        for (int nt = 0; nt < 8; nt++) acc[mt][nt] = (f4){0.f, 0.f, 0.f, 0.f};

#pragma unroll
    for (int ks = 0; ks < 4; ks++) {
        bf8 a[2], b[8];
#pragma unroll
        for (int mt = 0; mt < 2; mt++) {
            int node = w * 32 + mt * 16 + l15;
            int cs = (ks * 4 + quad) ^ (node & 15);
            a[mt] = *(const bf8*)&s5[node * 128 + cs * 8];
        }
#pragma unroll
        for (int nt = 0; nt < 8; nt++) {
            int o = nt * 16 + l15;
            int cs = (ks * 4 + quad) ^ (o & 15);
            b[nt] = *(const bf8*)&s5[16384 + o * 128 + cs * 8];
        }
#pragma unroll
        for (int mt = 0; mt < 2; mt++)
#pragma unroll
            for (int nt = 0; nt < 8; nt++)
                acc[mt][nt] = __builtin_amdgcn_mfma_f32_16x16x32_bf16(
                    a[mt], b[nt], acc[mt][nt], 0, 0, 0);
    }

    float b2v[8];
#pragma unroll
    for (int nt = 0; nt < 8; nt++) b2v[nt] = b2f[nt * 16 + l15];

#pragma unroll
    for (int mt = 0; mt < 2; mt++)
#pragma unroll
        for (int nt = 0; nt < 8; nt++)
#pragma unroll
            for (int r = 0; r < 4; r++) {
                int node = n0 + w * 32 + mt * 16 + quad * 4 + r;
                out[(size_t)node * 128 + nt * 16 + l15] = acc[mt][nt][r] + b2v[nt];
            }
}

extern "C" void kernel_launch(void* const* d_in, const int* in_sizes, int n_in,
                              void* d_out, int out_size, void* d_ws, size_t ws_size,
                              hipStream_t stream) {
    const float* x     = (const float*)d_in[0];
    const int*   ei    = (const int*)d_in[1];
    const float* W1    = (const float*)d_in[2];
    const float* b1    = (const float*)d_in[3];
    const float* u1    = (const float*)d_in[4];
    const float* gamma = (const float*)d_in[5];
    const float* beta  = (const float*)d_in[6];
    const float* W2    = (const float*)d_in[7];
    const float* b2    = (const float*)d_in[8];
    const float* u2    = (const float*)d_in[9];
    float* out = (float*)d_out;

    int N = in_sizes[0] / 64;     // 65536
    int E = in_sizes[1] / 2;      // 1048576
    int nblk = N / 128;           // 512

    char* ws = (char*)d_ws;
    size_t off = 0;
    short* hbf     = (short*)(ws + off); off += (size_t)N * 64 * 2;      // 8 MB
    char*  region2 = ws + off;           off += (size_t)N * 128 * 2;     // 16 MB
    unsigned* pairs = (unsigned*)region2;          // NB*CAP*4 = 5.25 MB (dies at k3)
    short*    h1bf  = (short*)region2;             // written by k3 after pairs dead
    int*   gcount  = (int*)(ws + off);   off += 1024;
    float* partial = (float*)(ws + off); off += (size_t)nblk * 256 * 4;  // 512 KB
    float* sinv    = (float*)(ws + off); off += 16 * 4;
    float* b2f     = (float*)(ws + off); off += 128 * 4;
    short* w1bf    = (short*)(ws + off); off += 128 * 64 * 2;
    short* w2fbf   = (short*)(ws + off); off += 128 * 128 * 2;

    // bucket counters -> 0
    kzero<<<1, 256, 0, stream>>>(gcount, NB);
    // bin edges into per-bucket packed lists (contiguous flushes)
    kbin<<<E / 4096, 256, 0, stream>>>(ei, E, gcount, pairs);
    // sigmas + W1 cast (small, independent)
    k2_sigma<<<1, 128, 0, stream>>>(W1, u1, W2, u2, sinv);
    kcvt<<<32, 256, 0, stream>>>(W1, w1bf, 128 * 64);
    // per-bucket aggregate: hbf = bf16(x + sum x[src])
    kaggb<<<NB, 512, 0, stream>>>(pairs, gcount, x, hbf);
    // h1 = relu(gemm1) -> bf16 + BN partials
    k3_gemm1<<<nblk, 256, 0, stream>>>(hbf, w1bf, b1, sinv, h1bf, partial);
    // fold BN + sigma2 into bf16 W2f
    k4_fold<<<1, 256, 0, stream>>>(partial, nblk, N, gamma, beta, W2, b2, sinv, w2fbf, b2f);
    // out = h1 @ W2f^T + b2f
    k5_gemm2<<<nblk, 256, 0, stream>>>(h1bf, w2fbf, b2f, out);
}

// Round 6
// 233.929 us; speedup vs baseline: 2.2631x; 2.2631x over previous
//
#include <hip/hip_runtime.h>

// N=65536, E=1048576, nfeat=64, nhid=128. Inputs fp32; edge_index int32.
// Aggregation: LDS-staged bucket binning (256 buckets x 256 nodes), then
// per-bucket LDS-CSR build + register accumulate (NO per-feature atomics).
// Gathers read bf16 x (half traffic). GEMMs: bf16 MFMA 16x16x32, fp32 acc.

#define BN_EPS 1e-5f
#define NB   256      // buckets
#define CAP  5120     // per-bucket capacity (avg 4096, +16 sigma)

typedef float f4 __attribute__((ext_vector_type(4)));
typedef short bf8 __attribute__((ext_vector_type(8)));   // 8 bf16 = 4 VGPRs

__device__ inline short f2bf(float f) {
    unsigned u = __float_as_uint(f);
    u = u + 0x7fffu + ((u >> 16) & 1u);   // round-to-nearest-even
    return (short)(u >> 16);
}
__device__ inline float bf2f(unsigned short u) {
    return __uint_as_float((unsigned)u << 16);
}

// ---------------- kzero: zero int array ----------------
__global__ __launch_bounds__(256) void kzero(int* __restrict__ p, int n) {
    int i = blockIdx.x * 256 + threadIdx.x;
    if (i < n) p[i] = 0;
}

// ---------------- kcvtx: fp32 x -> bf16 (packed) ----------------
__global__ __launch_bounds__(256) void kcvtx(const float2* __restrict__ x,
                                             unsigned* __restrict__ o, int n2) {
    int i = blockIdx.x * 256 + threadIdx.x;
    if (i < n2) {
        float2 v = x[i];
        o[i] = (unsigned)(unsigned short)f2bf(v.x) |
               ((unsigned)(unsigned short)f2bf(v.y) << 16);
    }
}

// ---------------- kbin: LDS-staged edge binning ----------------
// 256 blocks x 256 threads, 4096 edges/block. Packed edge in stage:
// [31:24]=bucket, [23:8]=src, [7:0]=dst&255. Flush per-bucket contiguous runs
// of (src<<8 | dst&255).
__global__ __launch_bounds__(256) void kbin(const int* __restrict__ ei, int E,
                                            int* __restrict__ gcount,
                                            unsigned* __restrict__ pairs) {
    __shared__ int hist[256];
    __shared__ int sbase[256];
    __shared__ int cur[256];
    __shared__ int gofs[256];
    __shared__ unsigned stage[4096];
    int t = threadIdx.x;
    int e0 = blockIdx.x * 4096;

    hist[t] = 0;
    __syncthreads();

    unsigned pk[16];
    int bk[16];
#pragma unroll
    for (int i = 0; i < 16; i++) {
        int e = e0 + i * 256 + t;
        int src = ei[e];
        int dst = ei[E + e];
        int b = dst >> 8;
        bk[i] = b;
        pk[i] = ((unsigned)b << 24) | ((unsigned)src << 8) | (unsigned)(dst & 255);
        atomicAdd(&hist[b], 1);
    }
    __syncthreads();

    int cntb = hist[t];
    for (int off = 1; off < 256; off <<= 1) {
        int v = (t >= off) ? hist[t - off] : 0;
        __syncthreads();
        hist[t] += v;
        __syncthreads();
    }
    int excl = hist[t] - cntb;
    sbase[t] = excl;
    cur[t] = excl;
    __syncthreads();

#pragma unroll
    for (int i = 0; i < 16; i++) {
        int p = atomicAdd(&cur[bk[i]], 1);
        stage[p] = pk[i];
    }
    __syncthreads();

    gofs[t] = atomicAdd(&gcount[t], cntb);
    __syncthreads();

#pragma unroll
    for (int i = 0; i < 16; i++) {
        int p = i * 256 + t;
        unsigned v = stage[p];
        int b = (int)(v >> 24);
        int li = p - sbase[b];
        pairs[(size_t)b * CAP + gofs[b] + li] = v & 0xFFFFFFu;
    }
}

// ---------------- kaggs: per-bucket LDS-CSR + register accumulate ----------------
// One 1024-thread block per bucket (256 nodes). Local CSR in LDS (1 LDS atomic
// per edge), then wave-per-node register accumulation, lane = feature.
// hbf[n] = bf16(x[n] + sum_{src->n} x[src]), gathered from bf16 x.
__global__ __launch_bounds__(1024) void kaggs(const unsigned* __restrict__ pairs,
                                              const int* __restrict__ gcount,
                                              const unsigned short* __restrict__ xbf,
                                              short* __restrict__ hbf) {
    __shared__ int hist[256];               // becomes inclusive scan (end offsets)
    __shared__ int offs[256];               // exclusive scan (begin offsets)
    __shared__ int cur[256];
    __shared__ unsigned short sorted[CAP];  // src indices, grouped by local dst
    int t = threadIdx.x;
    int b = blockIdx.x;
    int cnt = gcount[b];
    const unsigned* ep = pairs + (size_t)b * CAP;

    if (t < 256) hist[t] = 0;
    __syncthreads();
    for (int j = t; j < cnt; j += 1024) atomicAdd(&hist[ep[j] & 255u], 1);
    __syncthreads();
    int cntb = (t < 256) ? hist[t] : 0;
    for (int o = 1; o < 256; o <<= 1) {
        int v = (t < 256 && t >= o) ? hist[t - o] : 0;
        __syncthreads();
        if (t < 256) hist[t] += v;
        __syncthreads();
    }
    if (t < 256) { offs[t] = hist[t] - cntb; cur[t] = hist[t] - cntb; }
    __syncthreads();
    for (int j = t; j < cnt; j += 1024) {
        unsigned v = ep[j];
        int p = atomicAdd(&cur[v & 255u], 1);
        sorted[p] = (unsigned short)(v >> 8);
    }
    __syncthreads();

    int w = t >> 6, lane = t & 63;
#pragma unroll
    for (int ni = 0; ni < 16; ni++) {
        int n = w * 16 + ni;                 // local node
        int g = b * 256 + n;                 // global node
        int beg = offs[n], end = hist[n];
        float a0 = bf2f(xbf[(size_t)g * 64 + lane]);
        float a1 = 0.f, a2 = 0.f, a3 = 0.f;
        int j = beg;
        for (; j + 4 <= end; j += 4) {
            int s0 = sorted[j + 0];
            int s1 = sorted[j + 1];
            int s2 = sorted[j + 2];
            int s3 = sorted[j + 3];
            a0 += bf2f(xbf[(size_t)s0 * 64 + lane]);
            a1 += bf2f(xbf[(size_t)s1 * 64 + lane]);
            a2 += bf2f(xbf[(size_t)s2 * 64 + lane]);
            a3 += bf2f(xbf[(size_t)s3 * 64 + lane]);
        }
        for (; j < end; j++) a0 += bf2f(xbf[(size_t)sorted[j] * 64 + lane]);
        hbf[(size_t)g * 64 + lane] = f2bf((a0 + a1) + (a2 + a3));
    }
}

// ---------------- kcvt: fp32 -> bf16 (for W1) ----------------
__global__ __launch_bounds__(256) void kcvt(const float* __restrict__ w,
                                            short* __restrict__ o, int n) {
    int i = blockIdx.x * 256 + threadIdx.x;
    if (i < n) o[i] = f2bf(w[i]);
}

// ---------------- K2: spectral-norm sigmas (1 block, 128 thr, fp32) ----------------
__global__ __launch_bounds__(128) void k2_sigma(const float* __restrict__ W1,
                                                const float* __restrict__ u1,
                                                const float* __restrict__ W2,
                                                const float* __restrict__ u2,
                                                float* __restrict__ sinv) {
    __shared__ float v[128];
    __shared__ float red[128];
    int t = threadIdx.x;

    float vj = 0.f;
    if (t < 64) {
        for (int i = 0; i < 128; i++) vj += W1[i * 64 + t] * u1[i];
    }
    red[t] = (t < 64) ? vj * vj : 0.f;
    __syncthreads();
    for (int s = 64; s > 0; s >>= 1) { if (t < s) red[t] += red[t + s]; __syncthreads(); }
    float nv = sqrtf(red[0]);
    __syncthreads();
    if (t < 64) v[t] = vj / (nv + 1e-12f);
    __syncthreads();
    float ti = 0.f;
    for (int j = 0; j < 64; j++) ti += W1[t * 64 + j] * v[j];
    red[t] = ti * ti;
    __syncthreads();
    for (int s = 64; s > 0; s >>= 1) { if (t < s) red[t] += red[t + s]; __syncthreads(); }
    if (t == 0) {
        float nt2 = red[0];
        float nt = sqrtf(nt2);
        sinv[0] = (nt + 1e-12f) / nt2;
    }
    __syncthreads();

    float v2 = 0.f;
    for (int i = 0; i < 128; i++) v2 += W2[i * 128 + t] * u2[i];
    red[t] = v2 * v2;
    __syncthreads();
    for (int s = 64; s > 0; s >>= 1) { if (t < s) red[t] += red[t + s]; __syncthreads(); }
    nv = sqrtf(red[0]);
    __syncthreads();
    v[t] = v2 / (nv + 1e-12f);
    __syncthreads();
    ti = 0.f;
    for (int j = 0; j < 128; j++) ti += W2[t * 128 + j] * v[j];
    red[t] = ti * ti;
    __syncthreads();
    for (int s = 64; s > 0; s >>= 1) { if (t < s) red[t] += red[t + s]; __syncthreads(); }
    if (t == 0) {
        float nt2 = red[0];
        float nt = sqrtf(nt2);
        sinv[1] = (nt + 1e-12f) / nt2;
    }
}

// ---------------- K3: h1 = relu(s1*(h @ W1^T) + b1) via MFMA + BN partials ----
__global__ __launch_bounds__(256) void k3_gemm1(const short* __restrict__ hbf,
                                                const short* __restrict__ w1bf,
                                                const float* __restrict__ b1,
                                                const float* __restrict__ sinv,
                                                short* __restrict__ h1bf,
                                                float* __restrict__ partial) {
    __shared__ short u[16384];          // 32 KB
    __shared__ float red1[512], red2[512];
    int t = threadIdx.x;
    int n0 = blockIdx.x * 128;

    const bf8* hsrc = (const bf8*)(hbf + (size_t)n0 * 64);
    const bf8* wsrc = (const bf8*)w1bf;
#pragma unroll
    for (int i = 0; i < 4; i++) {
        int idx = i * 256 + t;
        int row = idx >> 3, c = idx & 7;
        int cs = c ^ (row & 7);
        *(bf8*)&u[row * 64 + cs * 8] = hsrc[idx];
    }
#pragma unroll
    for (int i = 0; i < 4; i++) {
        int idx = i * 256 + t;
        int row = idx >> 3, c = idx & 7;
        int cs = c ^ (row & 7);
        *(bf8*)&u[8192 + row * 64 + cs * 8] = wsrc[idx];
    }
    __syncthreads();

    int w = t >> 6;
    int l15 = t & 15, quad = (t & 63) >> 4;

    f4 acc[2][8];
#pragma unroll
    for (int mt = 0; mt < 2; mt++)
#pragma unroll
        for (int nt = 0; nt < 8; nt++) acc[mt][nt] = (f4){0.f, 0.f, 0.f, 0.f};

#pragma unroll
    for (int ks = 0; ks < 2; ks++) {
        bf8 a[2], b[8];
#pragma unroll
        for (int mt = 0; mt < 2; mt++) {
            int node = w * 32 + mt * 16 + l15;
            int cs = (ks * 4 + quad) ^ (node & 7);
            a[mt] = *(const bf8*)&u[node * 64 + cs * 8];
        }
#pragma unroll
        for (int nt = 0; nt < 8; nt++) {
            int o = nt * 16 + l15;
            int cs = (ks * 4 + quad) ^ (o & 7);
            b[nt] = *(const bf8*)&u[8192 + o * 64 + cs * 8];
        }
#pragma unroll
        for (int mt = 0; mt < 2; mt++)
#pragma unroll
            for (int nt = 0; nt < 8; nt++)
                acc[mt][nt] = __builtin_amdgcn_mfma_f32_16x16x32_bf16(
                    a[mt], b[nt], acc[mt][nt], 0, 0, 0);
    }

    float s1 = sinv[0];
    float b1v[8];
#pragma unroll
    for (int nt = 0; nt < 8; nt++) b1v[nt] = b1[nt * 16 + l15];

#pragma unroll
    for (int nt = 0; nt < 8; nt++) {
        float s = 0.f, q = 0.f;
#pragma unroll
        for (int mt = 0; mt < 2; mt++)
#pragma unroll
            for (int r = 0; r < 4; r++) {
                float v = fmaxf(fmaf(acc[mt][nt][r], s1, b1v[nt]), 0.f);
                acc[mt][nt][r] = v;
                s += v; q += v * v;
            }
        s += __shfl_xor(s, 16); s += __shfl_xor(s, 32);
        q += __shfl_xor(q, 16); q += __shfl_xor(q, 32);
        if (quad == 0) {
            red1[w * 128 + nt * 16 + l15] = s;
            red2[w * 128 + nt * 16 + l15] = q;
        }
    }
    __syncthreads();

#pragma unroll
    for (int mt = 0; mt < 2; mt++)
#pragma unroll
        for (int nt = 0; nt < 8; nt++) {
            int col = nt * 16 + l15;
#pragma unroll
            for (int r = 0; r < 4; r++) {
                int node = w * 32 + mt * 16 + quad * 4 + r;
                int cs = (col >> 3) ^ (node & 15);
                u[node * 128 + cs * 8 + (col & 7)] = f2bf(acc[mt][nt][r]);
            }
        }
    __syncthreads();

    short* dst = h1bf + (size_t)n0 * 128;
#pragma unroll
    for (int i = 0; i < 8; i++) {
        int idx = i * 256 + t;
        int row = idx >> 4, c = idx & 15;
        int cs = c ^ (row & 15);
        *(bf8*)&dst[idx * 8] = *(const bf8*)&u[row * 128 + cs * 8];
    }
    if (t < 128) {
        float s = red1[t] + red1[128 + t] + red1[256 + t] + red1[384 + t];
        float q = red2[t] + red2[128 + t] + red2[256 + t] + red2[384 + t];
        partial[blockIdx.x * 256 + t] = s;
        partial[blockIdx.x * 256 + 128 + t] = q;
    }
}

// ---------------- K4: fold BN + sigma2 into W2f(bf16), b2f(fp32) ----------------
__global__ __launch_bounds__(256) void k4_fold(const float* __restrict__ partial,
                                               int nblk, int N,
                                               const float* __restrict__ gamma,
                                               const float* __restrict__ beta,
                                               const float* __restrict__ W2,
                                               const float* __restrict__ b2,
                                               const float* __restrict__ sinv,
                                               short* __restrict__ W2fbf,
                                               float* __restrict__ b2f) {
    __shared__ float sums[256];
    __shared__ float a_s[128], c_s[128];
    int t = threadIdx.x;
    float t0 = 0.f, t1 = 0.f, t2 = 0.f, t3 = 0.f;
    for (int b = 0; b < nblk; b += 4) {
        t0 += partial[(b + 0) * 256 + t];
        t1 += partial[(b + 1) * 256 + t];
        t2 += partial[(b + 2) * 256 + t];
        t3 += partial[(b + 3) * 256 + t];
    }
    sums[t] = (t0 + t1) + (t2 + t3);
    __syncthreads();
    if (t < 128) {
        float mean = sums[t] / (float)N;
        float var = sums[t + 128] / (float)N - mean * mean;
        float rstd = rsqrtf(var + BN_EPS);
        float a = rstd * gamma[t];
        a_s[t] = a;
        c_s[t] = beta[t] - mean * a;
    }
    __syncthreads();
    if (t < 128) {
        float s2 = sinv[1];
        float accb = 0.f;
        for (int j = 0; j < 128; j++) {
            float w = W2[t * 128 + j] * s2;
            W2fbf[t * 128 + j] = f2bf(w * a_s[j]);
            accb += w * c_s[j];
        }
        b2f[t] = b2[t] + accb;
    }
}

// ---------------- K5: out = h1 @ W2f^T + b2f via MFMA ----------------
__global__ __launch_bounds__(256) void k5_gemm2(const short* __restrict__ h1bf,
                                                const short* __restrict__ w2fbf,
                                                const float* __restrict__ b2f,
                                                float* __restrict__ out) {
    __shared__ short s5[32768];
    int t = threadIdx.x;
    int n0 = blockIdx.x * 128;

    const bf8* hsrc = (const bf8*)(h1bf + (size_t)n0 * 128);
    const bf8* wsrc = (const bf8*)w2fbf;
#pragma unroll
    for (int i = 0; i < 8; i++) {
        int idx = i * 256 + t;
        int row = idx >> 4, c = idx & 15;
        int cs = c ^ (row & 15);
        *(bf8*)&s5[row * 128 + cs * 8] = hsrc[idx];
    }
#pragma unroll
    for (int i = 0; i < 8; i++) {
        int idx = i * 256 + t;
        int row = idx >> 4, c = idx & 15;
        int cs = c ^ (row & 15);
        *(bf8*)&s5[16384 + row * 128 + cs * 8] = wsrc[idx];
    }
    __syncthreads();

    int w = t >> 6;
    int l15 = t & 15, quad = (t & 63) >> 4;

    f4 acc[2][8];
#pragma unroll
    for (int mt = 0; mt < 2; mt++)
#pragma unroll
        for (int nt = 0; nt < 8; nt++) acc[mt][nt] = (f4){0.f, 0.f, 0.f, 0.f};

#pragma unroll
    for (int ks = 0; ks < 4; ks++) {
        bf8 a[2], b[8];
#pragma unroll
        for (int mt = 0; mt < 2; mt++) {
            int node = w * 32 + mt * 16 + l15;
            int cs = (ks * 4 + quad) ^ (node & 15);
            a[mt] = *(const bf8*)&s5[node * 128 + cs * 8];
        }
#pragma unroll
        for (int nt = 0; nt < 8; nt++) {
            int o = nt * 16 + l15;
            int cs = (ks * 4 + quad) ^ (o & 15);
            b[nt] = *(const bf8*)&s5[16384 + o * 128 + cs * 8];
        }
#pragma unroll
        for (int mt = 0; mt < 2; mt++)
#pragma unroll
            for (int nt = 0; nt < 8; nt++)
                acc[mt][nt] = __builtin_amdgcn_mfma_f32_16x16x32_bf16(
                    a[mt], b[nt], acc[mt][nt], 0, 0, 0);
    }

    float b2v[8];
#pragma unroll
    for (int nt = 0; nt < 8; nt++) b2v[nt] = b2f[nt * 16 + l15];

#pragma unroll
    for (int mt = 0; mt < 2; mt++)
#pragma unroll
        for (int nt = 0; nt < 8; nt++)
#pragma unroll
            for (int r = 0; r < 4; r++) {
                int node = n0 + w * 32 + mt * 16 + quad * 4 + r;
                out[(size_t)node * 128 + nt * 16 + l15] = acc[mt][nt][r] + b2v[nt];
            }
}

extern "C" void kernel_launch(void* const* d_in, const int* in_sizes, int n_in,
                              void* d_out, int out_size, void* d_ws, size_t ws_size,
                              hipStream_t stream) {
    const float* x     = (const float*)d_in[0];
    const int*   ei    = (const int*)d_in[1];
    const float* W1    = (const float*)d_in[2];
    const float* b1    = (const float*)d_in[3];
    const float* u1    = (const float*)d_in[4];
    const float* gamma = (const float*)d_in[5];
    const float* beta  = (const float*)d_in[6];
    const float* W2    = (const float*)d_in[7];
    const float* b2    = (const float*)d_in[8];
    const float* u2    = (const float*)d_in[9];
    float* out = (float*)d_out;

    int N = in_sizes[0] / 64;     // 65536
    int E = in_sizes[1] / 2;      // 1048576
    int nblk = N / 128;           // 512

    char* ws = (char*)d_ws;
    size_t off = 0;
    short* hbf     = (short*)(ws + off); off += (size_t)N * 64 * 2;      // 8 MB
    char*  region2 = ws + off;           off += (size_t)N * 128 * 2;     // 16 MB
    // region2 lifetime: [pairs 5.25MB | xbf 8MB] die after kaggs; then h1bf.
    unsigned* pairs = (unsigned*)region2;
    unsigned short* xbf = (unsigned short*)(region2 + (size_t)NB * CAP * 4);
    short*    h1bf  = (short*)region2;
    int*   gcount  = (int*)(ws + off);   off += 1024;
    float* partial = (float*)(ws + off); off += (size_t)nblk * 256 * 4;  // 512 KB
    float* sinv    = (float*)(ws + off); off += 16 * 4;
    float* b2f     = (float*)(ws + off); off += 128 * 4;
    short* w1bf    = (short*)(ws + off); off += 128 * 64 * 2;
    short* w2fbf   = (short*)(ws + off); off += 128 * 128 * 2;

    // bucket counters -> 0
    kzero<<<1, 256, 0, stream>>>(gcount, NB);
    // bin edges into per-bucket packed lists (contiguous flushes)
    kbin<<<E / 4096, 256, 0, stream>>>(ei, E, gcount, pairs);
    // x -> bf16 (halves gather traffic)
    kcvtx<<<(N * 32 + 255) / 256, 256, 0, stream>>>((const float2*)x,
                                                    (unsigned*)xbf, N * 32);
    // sigmas + W1 cast (small, independent)
    k2_sigma<<<1, 128, 0, stream>>>(W1, u1, W2, u2, sinv);
    kcvt<<<32, 256, 0, stream>>>(W1, w1bf, 128 * 64);
    // per-bucket LDS-CSR + register aggregate: hbf = bf16(x + sum x[src])
    kaggs<<<NB, 1024, 0, stream>>>(pairs, gcount, xbf, hbf);
    // h1 = relu(gemm1) -> bf16 + BN partials
    k3_gemm1<<<nblk, 256, 0, stream>>>(hbf, w1bf, b1, sinv, h1bf, partial);
    // fold BN + sigma2 into bf16 W2f
    k4_fold<<<1, 256, 0, stream>>>(partial, nblk, N, gamma, beta, W2, b2, sinv, w2fbf, b2f);
    // out = h1 @ W2f^T + b2f
    k5_gemm2<<<nblk, 256, 0, stream>>>(h1bf, w2fbf, b2f, out);
}

// Round 7
// 195.698 us; speedup vs baseline: 2.7052x; 1.1954x over previous
//
#include <hip/hip_runtime.h>

// N=65536, E=1048576, nfeat=64, nhid=128. Inputs fp32; edge_index int32.
// Aggregation: LDS-staged bucket binning (256 buckets x 256 nodes), then
// per-bucket LDS-CSR build + half-wave-paired register gather (no per-feature
// atomics). Gathers read bf16 x. GEMMs: bf16 MFMA 16x16x32, fp32 acc.
// BN stats: per-block LDS reduce in k3 -> 256-float global atomic accumulator.

#define BN_EPS 1e-5f
#define NB   256      // buckets
#define CAP  5120     // per-bucket capacity (avg 4096, +16 sigma)

typedef float f4 __attribute__((ext_vector_type(4)));
typedef short bf8 __attribute__((ext_vector_type(8)));   // 8 bf16 = 4 VGPRs

__device__ inline short f2bf(float f) {
    unsigned u = __float_as_uint(f);
    u = u + 0x7fffu + ((u >> 16) & 1u);   // round-to-nearest-even
    return (short)(u >> 16);
}
__device__ inline float bf2f(unsigned short u) {
    return __uint_as_float((unsigned)u << 16);
}

// ---------------- kzero: zero int array ----------------
__global__ __launch_bounds__(256) void kzero(int* __restrict__ p, int n) {
    int i = blockIdx.x * 256 + threadIdx.x;
    if (i < n) p[i] = 0;
}

// ---------------- kcvtx: fp32 x -> bf16 (packed) ----------------
__global__ __launch_bounds__(256) void kcvtx(const float2* __restrict__ x,
                                             unsigned* __restrict__ o, int n2) {
    int i = blockIdx.x * 256 + threadIdx.x;
    if (i < n2) {
        float2 v = x[i];
        o[i] = (unsigned)(unsigned short)f2bf(v.x) |
               ((unsigned)(unsigned short)f2bf(v.y) << 16);
    }
}

// ---------------- kbin: LDS-staged edge binning ----------------
// 256 blocks x 256 threads, 4096 edges/block. Packed edge in stage:
// [31:24]=bucket, [23:8]=src, [7:0]=dst&255. Flush per-bucket contiguous runs
// of (src<<8 | dst&255).
__global__ __launch_bounds__(256) void kbin(const int* __restrict__ ei, int E,
                                            int* __restrict__ gcount,
                                            unsigned* __restrict__ pairs) {
    __shared__ int hist[256];
    __shared__ int sbase[256];
    __shared__ int cur[256];
    __shared__ int gofs[256];
    __shared__ unsigned stage[4096];
    int t = threadIdx.x;
    int e0 = blockIdx.x * 4096;

    hist[t] = 0;
    __syncthreads();

    unsigned pk[16];
    int bk[16];
#pragma unroll
    for (int i = 0; i < 16; i++) {
        int e = e0 + i * 256 + t;
        int src = ei[e];
        int dst = ei[E + e];
        int b = dst >> 8;
        bk[i] = b;
        pk[i] = ((unsigned)b << 24) | ((unsigned)src << 8) | (unsigned)(dst & 255);
        atomicAdd(&hist[b], 1);
    }
    __syncthreads();

    int cntb = hist[t];
    for (int off = 1; off < 256; off <<= 1) {
        int v = (t >= off) ? hist[t - off] : 0;
        __syncthreads();
        hist[t] += v;
        __syncthreads();
    }
    int excl = hist[t] - cntb;
    sbase[t] = excl;
    cur[t] = excl;
    __syncthreads();

#pragma unroll
    for (int i = 0; i < 16; i++) {
        int p = atomicAdd(&cur[bk[i]], 1);
        stage[p] = pk[i];
    }
    __syncthreads();

    gofs[t] = atomicAdd(&gcount[t], cntb);
    __syncthreads();

#pragma unroll
    for (int i = 0; i < 16; i++) {
        int p = i * 256 + t;
        unsigned v = stage[p];
        int b = (int)(v >> 24);
        int li = p - sbase[b];
        pairs[(size_t)b * CAP + gofs[b] + li] = v & 0xFFFFFFu;
    }
}

// ---------------- kaggs: per-bucket LDS-CSR + paired register gather ----------
// One 1024-thread block per bucket (256 nodes). Local CSR in LDS (1 LDS atomic
// per edge), then wave-per-node accumulation: half-wave h handles edges of
// parity h; lane = feature-pair (uint = 2 bf16). __shfl_xor(32) combines.
__global__ __launch_bounds__(1024) void kaggs(const unsigned* __restrict__ pairs,
                                              const int* __restrict__ gcount,
                                              const unsigned* __restrict__ xbf2,
                                              unsigned* __restrict__ hbf2) {
    __shared__ unsigned ep[CAP];            // staged pairs (20 KB)
    __shared__ unsigned short sorted[CAP];  // src16 grouped by local dst (10 KB)
    __shared__ int hist[256];               // inclusive scan (end offsets)
    __shared__ int offs[256];               // exclusive scan (begin offsets)
    __shared__ int cur[256];
    int t = threadIdx.x;
    int b = blockIdx.x;
    int cnt = gcount[b];
    const unsigned* gp = pairs + (size_t)b * CAP;

    if (t < 256) hist[t] = 0;
    for (int j = t; j < cnt; j += 1024) ep[j] = gp[j];
    __syncthreads();
    for (int j = t; j < cnt; j += 1024) atomicAdd(&hist[ep[j] & 255u], 1);
    __syncthreads();
    int cntb = (t < 256) ? hist[t] : 0;
    for (int o = 1; o < 256; o <<= 1) {
        int v = (t < 256 && t >= o) ? hist[t - o] : 0;
        __syncthreads();
        if (t < 256) hist[t] += v;
        __syncthreads();
    }
    if (t < 256) { offs[t] = hist[t] - cntb; cur[t] = hist[t] - cntb; }
    __syncthreads();
    for (int j = t; j < cnt; j += 1024) {
        unsigned v = ep[j];
        int p = atomicAdd(&cur[v & 255u], 1);
        sorted[p] = (unsigned short)(v >> 8);
    }
    __syncthreads();

    int w = t >> 6;
    int lane = t & 63;
    int h = lane >> 5;        // half-wave: edge parity
    int l = lane & 31;        // feature-pair index (features 2l, 2l+1)

#pragma unroll
    for (int ni = 0; ni < 16; ni++) {
        int n = w * 16 + ni;                 // local node
        int g = b * 256 + n;                 // global node
        int beg = offs[n], end = hist[n];
        float a0 = 0.f, a1 = 0.f, b0 = 0.f, b1 = 0.f;
        float c0 = 0.f, c1 = 0.f, d0 = 0.f, d1 = 0.f;
        int j = beg + h;
        for (; j + 6 < end; j += 8) {
            int s0 = sorted[j];
            int s1 = sorted[j + 2];
            int s2 = sorted[j + 4];
            int s3 = sorted[j + 6];
            unsigned v0 = xbf2[(size_t)s0 * 32 + l];
            unsigned v1 = xbf2[(size_t)s1 * 32 + l];
            unsigned v2 = xbf2[(size_t)s2 * 32 + l];
            unsigned v3 = xbf2[(size_t)s3 * 32 + l];
            a0 += bf2f((unsigned short)v0); a1 += bf2f((unsigned short)(v0 >> 16));
            b0 += bf2f((unsigned short)v1); b1 += bf2f((unsigned short)(v1 >> 16));
            c0 += bf2f((unsigned short)v2); c1 += bf2f((unsigned short)(v2 >> 16));
            d0 += bf2f((unsigned short)v3); d1 += bf2f((unsigned short)(v3 >> 16));
        }
        for (; j < end; j += 2) {
            unsigned v = xbf2[(size_t)sorted[j] * 32 + l];
            a0 += bf2f((unsigned short)v); a1 += bf2f((unsigned short)(v >> 16));
        }
        a0 = (a0 + b0) + (c0 + d0);
        a1 = (a1 + b1) + (c1 + d1);
        a0 += __shfl_xor(a0, 32);
        a1 += __shfl_xor(a1, 32);
        unsigned xs = xbf2[(size_t)g * 32 + l];
        a0 += bf2f((unsigned short)xs);
        a1 += bf2f((unsigned short)(xs >> 16));
        if (h == 0) {
            unsigned p = (unsigned)(unsigned short)f2bf(a0) |
                         ((unsigned)(unsigned short)f2bf(a1) << 16);
            hbf2[(size_t)g * 32 + l] = p;
        }
    }
}

// ---------------- kcvt: fp32 -> bf16 (for W1) ----------------
__global__ __launch_bounds__(256) void kcvt(const float* __restrict__ w,
                                            short* __restrict__ o, int n) {
    int i = blockIdx.x * 256 + threadIdx.x;
    if (i < n) o[i] = f2bf(w[i]);
}

// ---------------- K2: spectral-norm sigmas (1 block, 128 thr, fp32) ----------------
__global__ __launch_bounds__(128) void k2_sigma(const float* __restrict__ W1,
                                                const float* __restrict__ u1,
                                                const float* __restrict__ W2,
                                                const float* __restrict__ u2,
                                                float* __restrict__ sinv) {
    __shared__ float v[128];
    __shared__ float red[128];
    int t = threadIdx.x;

    float vj = 0.f;
    if (t < 64) {
        for (int i = 0; i < 128; i++) vj += W1[i * 64 + t] * u1[i];
    }
    red[t] = (t < 64) ? vj * vj : 0.f;
    __syncthreads();
    for (int s = 64; s > 0; s >>= 1) { if (t < s) red[t] += red[t + s]; __syncthreads(); }
    float nv = sqrtf(red[0]);
    __syncthreads();
    if (t < 64) v[t] = vj / (nv + 1e-12f);
    __syncthreads();
    float ti = 0.f;
    for (int j = 0; j < 64; j++) ti += W1[t * 64 + j] * v[j];
    red[t] = ti * ti;
    __syncthreads();
    for (int s = 64; s > 0; s >>= 1) { if (t < s) red[t] += red[t + s]; __syncthreads(); }
    if (t == 0) {
        float nt2 = red[0];
        float nt = sqrtf(nt2);
        sinv[0] = (nt + 1e-12f) / nt2;
    }
    __syncthreads();

    float v2 = 0.f;
    for (int i = 0; i < 128; i++) v2 += W2[i * 128 + t] * u2[i];
    red[t] = v2 * v2;
    __syncthreads();
    for (int s = 64; s > 0; s >>= 1) { if (t < s) red[t] += red[t + s]; __syncthreads(); }
    nv = sqrtf(red[0]);
    __syncthreads();
    v[t] = v2 / (nv + 1e-12f);
    __syncthreads();
    ti = 0.f;
    for (int j = 0; j < 128; j++) ti += W2[t * 128 + j] * v[j];
    red[t] = ti * ti;
    __syncthreads();
    for (int s = 64; s > 0; s >>= 1) { if (t < s) red[t] += red[t + s]; __syncthreads(); }
    if (t == 0) {
        float nt2 = red[0];
        float nt = sqrtf(nt2);
        sinv[1] = (nt + 1e-12f) / nt2;
    }
}

// ---------------- K3: h1 = relu(s1*(h @ W1^T) + b1) via MFMA + BN atomics ----
__global__ __launch_bounds__(256) void k3_gemm1(const short* __restrict__ hbf,
                                                const short* __restrict__ w1bf,
                                                const float* __restrict__ b1,
                                                const float* __restrict__ sinv,
                                                short* __restrict__ h1bf,
                                                float* __restrict__ bnacc) {
    __shared__ short u[16384];          // 32 KB
    __shared__ float red1[512], red2[512];
    int t = threadIdx.x;
    int n0 = blockIdx.x * 128;

    const bf8* hsrc = (const bf8*)(hbf + (size_t)n0 * 64);
    const bf8* wsrc = (const bf8*)w1bf;
#pragma unroll
    for (int i = 0; i < 4; i++) {
        int idx = i * 256 + t;
        int row = idx >> 3, c = idx & 7;
        int cs = c ^ (row & 7);
        *(bf8*)&u[row * 64 + cs * 8] = hsrc[idx];
    }
#pragma unroll
    for (int i = 0; i < 4; i++) {
        int idx = i * 256 + t;
        int row = idx >> 3, c = idx & 7;
        int cs = c ^ (row & 7);
        *(bf8*)&u[8192 + row * 64 + cs * 8] = wsrc[idx];
    }
    __syncthreads();

    int w = t >> 6;
    int l15 = t & 15, quad = (t & 63) >> 4;

    f4 acc[2][8];
#pragma unroll
    for (int mt = 0; mt < 2; mt++)
#pragma unroll
        for (int nt = 0; nt < 8; nt++) acc[mt][nt] = (f4){0.f, 0.f, 0.f, 0.f};

#pragma unroll
    for (int ks = 0; ks < 2; ks++) {
        bf8 a[2], b[8];
#pragma unroll
        for (int mt = 0; mt < 2; mt++) {
            int node = w * 32 + mt * 16 + l15;
            int cs = (ks * 4 + quad) ^ (node & 7);
            a[mt] = *(const bf8*)&u[node * 64 + cs * 8];
        }
#pragma unroll
        for (int nt = 0; nt < 8; nt++) {
            int o = nt * 16 + l15;
            int cs = (ks * 4 + quad) ^ (o & 7);
            b[nt] = *(const bf8*)&u[8192 + o * 64 + cs * 8];
        }
#pragma unroll
        for (int mt = 0; mt < 2; mt++)
#pragma unroll
            for (int nt = 0; nt < 8; nt++)
                acc[mt][nt] = __builtin_amdgcn_mfma_f32_16x16x32_bf16(
                    a[mt], b[nt], acc[mt][nt], 0, 0, 0);
    }

    float s1 = sinv[0];
    float b1v[8];
#pragma unroll
    for (int nt = 0; nt < 8; nt++) b1v[nt] = b1[nt * 16 + l15];

#pragma unroll
    for (int nt = 0; nt < 8; nt++) {
        float s = 0.f, q = 0.f;
#pragma unroll
        for (int mt = 0; mt < 2; mt++)
#pragma unroll
            for (int r = 0; r < 4; r++) {
                float v = fmaxf(fmaf(acc[mt][nt][r], s1, b1v[nt]), 0.f);
                acc[mt][nt][r] = v;
                s += v; q += v * v;
            }
        s += __shfl_xor(s, 16); s += __shfl_xor(s, 32);
        q += __shfl_xor(q, 16); q += __shfl_xor(q, 32);
        if (quad == 0) {
            red1[w * 128 + nt * 16 + l15] = s;
            red2[w * 128 + nt * 16 + l15] = q;
        }
    }
    __syncthreads();

#pragma unroll
    for (int mt = 0; mt < 2; mt++)
#pragma unroll
        for (int nt = 0; nt < 8; nt++) {
            int col = nt * 16 + l15;
#pragma unroll
            for (int r = 0; r < 4; r++) {
                int node = w * 32 + mt * 16 + quad * 4 + r;
                int cs = (col >> 3) ^ (node & 15);
                u[node * 128 + cs * 8 + (col & 7)] = f2bf(acc[mt][nt][r]);
            }
        }
    __syncthreads();

    short* dst = h1bf + (size_t)n0 * 128;
#pragma unroll
    for (int i = 0; i < 8; i++) {
        int idx = i * 256 + t;
        int row = idx >> 4, c = idx & 15;
        int cs = c ^ (row & 15);
        *(bf8*)&dst[idx * 8] = *(const bf8*)&u[row * 128 + cs * 8];
    }
    if (t < 128) {
        float s = red1[t] + red1[128 + t] + red1[256 + t] + red1[384 + t];
        float q = red2[t] + red2[128 + t] + red2[256 + t] + red2[384 + t];
        atomicAdd(&bnacc[t], s);
        atomicAdd(&bnacc[128 + t], q);
    }
}

// ---------------- K4: fold BN + sigma2 into W2f(bf16), b2f(fp32) ----------------
__global__ __launch_bounds__(128) void k4_fold(const float* __restrict__ bnacc,
                                               int N,
                                               const float* __restrict__ gamma,
                                               const float* __restrict__ beta,
                                               const float* __restrict__ W2,
                                               const float* __restrict__ b2,
                                               const float* __restrict__ sinv,
                                               short* __restrict__ W2fbf,
                                               float* __restrict__ b2f) {
    __shared__ float a_s[128], c_s[128];
    int t = threadIdx.x;
    {
        float mean = bnacc[t] / (float)N;
        float var = bnacc[t + 128] / (float)N - mean * mean;
        float rstd = rsqrtf(var + BN_EPS);
        float a = rstd * gamma[t];
        a_s[t] = a;
        c_s[t] = beta[t] - mean * a;
    }
    __syncthreads();
    float s2 = sinv[1];
    float accb = 0.f;
    for (int j = 0; j < 128; j++) {
        float w = W2[t * 128 + j] * s2;
        W2fbf[t * 128 + j] = f2bf(w * a_s[j]);
        accb += w * c_s[j];
    }
    b2f[t] = b2[t] + accb;
}

// ---------------- K5: out = h1 @ W2f^T + b2f via MFMA ----------------
__global__ __launch_bounds__(256) void k5_gemm2(const short* __restrict__ h1bf,
                                                const short* __restrict__ w2fbf,
                                                const float* __restrict__ b2f,
                                                float* __restrict__ out) {
    __shared__ short s5[32768];
    int t = threadIdx.x;
    int n0 = blockIdx.x * 128;

    const bf8* hsrc = (const bf8*)(h1bf + (size_t)n0 * 128);
    const bf8* wsrc = (const bf8*)w2fbf;
#pragma unroll
    for (int i = 0; i < 8; i++) {
        int idx = i * 256 + t;
        int row = idx >> 4, c = idx & 15;
        int cs = c ^ (row & 15);
        *(bf8*)&s5[row * 128 + cs * 8] = hsrc[idx];
    }
#pragma unroll
    for (int i = 0; i < 8; i++) {
        int idx = i * 256 + t;
        int row = idx >> 4, c = idx & 15;
        int cs = c ^ (row & 15);
        *(bf8*)&s5[16384 + row * 128 + cs * 8] = wsrc[idx];
    }
    __syncthreads();

    int w = t >> 6;
    int l15 = t & 15, quad = (t & 63) >> 4;

    f4 acc[2][8];
#pragma unroll
    for (int mt = 0; mt < 2; mt++)
#pragma unroll
        for (int nt = 0; nt < 8; nt++) acc[mt][nt] = (f4){0.f, 0.f, 0.f, 0.f};

#pragma unroll
    for (int ks = 0; ks < 4; ks++) {
        bf8 a[2], b[8];
#pragma unroll
        for (int mt = 0; mt < 2; mt++) {
            int node = w * 32 + mt * 16 + l15;
            int cs = (ks * 4 + quad) ^ (node & 15);
            a[mt] = *(const bf8*)&s5[node * 128 + cs * 8];
        }
#pragma unroll
        for (int nt = 0; nt < 8; nt++) {
            int o = nt * 16 + l15;
            int cs = (ks * 4 + quad) ^ (o & 15);
            b[nt] = *(const bf8*)&s5[16384 + o * 128 + cs * 8];
        }
#pragma unroll
        for (int mt = 0; mt < 2; mt++)
#pragma unroll
            for (int nt = 0; nt < 8; nt++)
                acc[mt][nt] = __builtin_amdgcn_mfma_f32_16x16x32_bf16(
                    a[mt], b[nt], acc[mt][nt], 0, 0, 0);
    }

    float b2v[8];
#pragma unroll
    for (int nt = 0; nt < 8; nt++) b2v[nt] = b2f[nt * 16 + l15];

#pragma unroll
    for (int mt = 0; mt < 2; mt++)
#pragma unroll
        for (int nt = 0; nt < 8; nt++)
#pragma unroll
            for (int r = 0; r < 4; r++) {
                int node = n0 + w * 32 + mt * 16 + quad * 4 + r;
                out[(size_t)node * 128 + nt * 16 + l15] = acc[mt][nt][r] + b2v[nt];
            }
}

extern "C" void kernel_launch(void* const* d_in, const int* in_sizes, int n_in,
                              void* d_out, int out_size, void* d_ws, size_t ws_size,
                              hipStream_t stream) {
    const float* x     = (const float*)d_in[0];
    const int*   ei    = (const int*)d_in[1];
    const float* W1    = (const float*)d_in[2];
    const float* b1    = (const float*)d_in[3];
    const float* u1    = (const float*)d_in[4];
    const float* gamma = (const float*)d_in[5];
    const float* beta  = (const float*)d_in[6];
    const float* W2    = (const float*)d_in[7];
    const float* b2    = (const float*)d_in[8];
    const float* u2    = (const float*)d_in[9];
    float* out = (float*)d_out;

    int N = in_sizes[0] / 64;     // 65536
    int E = in_sizes[1] / 2;      // 1048576
    int nblk = N / 128;           // 512

    char* ws = (char*)d_ws;
    size_t off = 0;
    short* hbf     = (short*)(ws + off); off += (size_t)N * 64 * 2;      // 8 MB
    char*  region2 = ws + off;           off += (size_t)N * 128 * 2;     // 16 MB
    // region2 lifetime: [pairs 5.25MB | xbf 8MB] die after kaggs; then h1bf.
    unsigned* pairs = (unsigned*)region2;
    unsigned short* xbf = (unsigned short*)(region2 + (size_t)NB * CAP * 4);
    short*    h1bf  = (short*)region2;
    int*   gcount  = (int*)(ws + off);   off += 256 * 4;
    float* bnacc   = (float*)(ws + off); off += 256 * 4;   // contiguous w/ gcount
    float* sinv    = (float*)(ws + off); off += 16 * 4;
    float* b2f     = (float*)(ws + off); off += 128 * 4;
    short* w1bf    = (short*)(ws + off); off += 128 * 64 * 2;
    short* w2fbf   = (short*)(ws + off); off += 128 * 128 * 2;

    // zero gcount (256 ints) + bnacc (256 floats) in one launch
    kzero<<<2, 256, 0, stream>>>(gcount, 512);
    // bin edges into per-bucket packed lists (contiguous flushes)
    kbin<<<E / 4096, 256, 0, stream>>>(ei, E, gcount, pairs);
    // x -> bf16 (halves gather traffic)
    kcvtx<<<(N * 32 + 255) / 256, 256, 0, stream>>>((const float2*)x,
                                                    (unsigned*)xbf, N * 32);
    // sigmas + W1 cast (small, independent)
    k2_sigma<<<1, 128, 0, stream>>>(W1, u1, W2, u2, sinv);
    kcvt<<<32, 256, 0, stream>>>(W1, w1bf, 128 * 64);
    // per-bucket LDS-CSR + paired register gather: hbf = bf16(x + sum x[src])
    kaggs<<<NB, 1024, 0, stream>>>(pairs, gcount, (const unsigned*)xbf,
                                   (unsigned*)hbf);
    // h1 = relu(gemm1) -> bf16 + BN atomic accumulation
    k3_gemm1<<<nblk, 256, 0, stream>>>(hbf, w1bf, b1, sinv, h1bf, bnacc);
    // fold BN + sigma2 into bf16 W2f
    k4_fold<<<1, 128, 0, stream>>>(bnacc, N, gamma, beta, W2, b2, sinv, w2fbf, b2f);
    // out = h1 @ W2f^T + b2f
    k5_gemm2<<<nblk, 256, 0, stream>>>(h1bf, w2fbf, b2f, out);
}